// Round 2
// baseline (653.341 us; speedup 1.0000x reference)
//
#include <hip/hip_runtime.h>

// MultiMiniInterv: out = base; for 4 fixed 16-wide channel regions g at
// STARTS={0,752,184,568}: out[:, s:s+16] += ((Ws_g - Wp_g) x + (bs_g - bp_g)) @ Wp_g
// base: [1, B=131072, 768] f32; Wp/Ws: [4, 8, 16]; bp/bs: [4, 8].
//
// Memory-bound (805 MB floor => ~128 us @ 6.3 TB/s achievable).
// This version: per-lane fused 16->4 affine map precomputed in REGISTERS
// (M[e][j] = sum_r Wd[r,e]*Wp[r,off+j]; dv[j] = sum_r bd[r]*Wp[r,off+j]),
// so the hot loop has ZERO LDS reads and 64 reg-only FMAs per region row
// (was: 160 ds_read_b32 + 160 FMA). 4-row load batching for MLP depth,
// nontemporal stores for the pure write stream, grid-stride 2048 blocks.

typedef float f4 __attribute__((ext_vector_type(4)));

constexpr int F4_PER_ROW   = 192;   // 768 / 4
constexpr int ROWS_PER_ITER = 4;
constexpr int BLOCK = 192;
constexpr int MAX_BLOCKS = 2048;

__global__ __launch_bounds__(BLOCK) void multi_mini_interv_kernel(
    const float* __restrict__ base,
    const float* __restrict__ Wp,
    const float* __restrict__ bp,
    const float* __restrict__ Ws,
    const float* __restrict__ bs,
    float* __restrict__ out,
    int B)
{
    __shared__ float sWp[512];   // [g][r][e] = [4][8][16]
    __shared__ float sWd[512];   // Ws - Wp
    __shared__ float sbd[32];    // bs - bp, [4][8]

    const int tid = threadIdx.x;

    // Stage weights into LDS (prologue only; hot loop never touches LDS)
    for (int i = tid; i < 512; i += BLOCK) {
        float wp = Wp[i];
        sWp[i] = wp;
        sWd[i] = Ws[i] - wp;
    }
    if (tid < 32) sbd[tid] = bs[tid] - bp[tid];
    __syncthreads();

    // Per-lane constant: which region (if any) does this float4 column touch?
    // f4 col ranges: g0: 0..3 (ch 0..15), g1: 188..191 (752..767),
    //                g2: 46..49 (184..199), g3: 142..145 (568..583)
    const int c = tid;   // float4 column in row, 0..191
    int g = -1, cbase = 0;
    if (c < 4)                    { g = 0; cbase = 0;   }
    else if (c >= 188)            { g = 1; cbase = 188; }
    else if (c >= 46 && c < 50)   { g = 2; cbase = 46;  }
    else if (c >= 142 && c < 146) { g = 3; cbase = 142; }
    const int off = (c - cbase) * 4;   // this lane's 4 channels within the 16-wide region

    // Collapse the rank-8 operator into a per-lane fused 16->4 affine map:
    //   delta[off+j] = dv[j] + sum_e x[e] * M[e][j]
    //   M[e][j] = sum_r Wd[r][e] * Wp[r][off+j];  dv[j] = sum_r bd[r] * Wp[r][off+j]
    // 64 VGPRs of M per lane, computed once per block. Statically indexed
    // everywhere (stays in registers, no scratch).
    float M[16][4];
    float dv[4] = {0.f, 0.f, 0.f, 0.f};
    if (g >= 0) {
        #pragma unroll
        for (int e = 0; e < 16; ++e) {
            M[e][0] = 0.f; M[e][1] = 0.f; M[e][2] = 0.f; M[e][3] = 0.f;
        }
        const float* wd = &sWd[g * 128];
        const float* wp = &sWp[g * 128 + off];
        #pragma unroll
        for (int r = 0; r < 8; ++r) {
            const float w0 = wp[r * 16 + 0];
            const float w1 = wp[r * 16 + 1];
            const float w2 = wp[r * 16 + 2];
            const float w3 = wp[r * 16 + 3];
            const float bd = sbd[g * 8 + r];
            dv[0] += bd * w0; dv[1] += bd * w1; dv[2] += bd * w2; dv[3] += bd * w3;
            #pragma unroll
            for (int e = 0; e < 16; ++e) {
                const float wde = wd[r * 16 + e];
                M[e][0] += wde * w0; M[e][1] += wde * w1;
                M[e][2] += wde * w2; M[e][3] += wde * w3;
            }
        }
    }

    const f4* __restrict__ base4 = (const f4*)base;
    f4* __restrict__ out4 = (f4*)out;

    const int ngroups_full = B / ROWS_PER_ITER;

    // Grid-stride over 4-row groups: batch all loads, then compute, then store.
    for (int grp = blockIdx.x; grp < ngroups_full; grp += gridDim.x) {
        const size_t row0 = (size_t)grp * ROWS_PER_ITER;
        const f4* __restrict__ src = base4 + row0 * F4_PER_ROW;
        f4* __restrict__ dst = out4 + row0 * F4_PER_ROW;

        f4 v[ROWS_PER_ITER];
        #pragma unroll
        for (int rr = 0; rr < ROWS_PER_ITER; ++rr)
            v[rr] = src[rr * F4_PER_ROW + c];

        if (g >= 0) {
            #pragma unroll
            for (int rr = 0; rr < ROWS_PER_ITER; ++rr) {
                // Re-read the 16-wide region (same cache lines as the wave's
                // own v-loads -> L1/L2 hits; no extra HBM traffic).
                const f4* s = src + rr * F4_PER_ROW + cbase;
                f4 x0 = s[0], x1 = s[1], x2 = s[2], x3 = s[3];
                float x[16];
                #pragma unroll
                for (int q = 0; q < 4; ++q) {
                    x[q]      = x0[q];
                    x[4 + q]  = x1[q];
                    x[8 + q]  = x2[q];
                    x[12 + q] = x3[q];
                }
                float d0 = dv[0], d1 = dv[1], d2 = dv[2], d3 = dv[3];
                #pragma unroll
                for (int e = 0; e < 16; ++e) {
                    d0 += x[e] * M[e][0];
                    d1 += x[e] * M[e][1];
                    d2 += x[e] * M[e][2];
                    d3 += x[e] * M[e][3];
                }
                v[rr][0] += d0; v[rr][1] += d1; v[rr][2] += d2; v[rr][3] += d3;
            }
        }

        #pragma unroll
        for (int rr = 0; rr < ROWS_PER_ITER; ++rr)
            __builtin_nontemporal_store(v[rr], &dst[rr * F4_PER_ROW + c]);
    }

    // Tail rows (B % 4 != 0 — not hit for B=131072, kept for correctness)
    const int tail0 = ngroups_full * ROWS_PER_ITER;
    for (int row = tail0 + blockIdx.x; row < B; row += gridDim.x) {
        const f4* __restrict__ s = base4 + (size_t)row * F4_PER_ROW;
        f4 v = s[c];
        if (g >= 0) {
            f4 x0 = s[cbase + 0], x1 = s[cbase + 1], x2 = s[cbase + 2], x3 = s[cbase + 3];
            float x[16];
            #pragma unroll
            for (int q = 0; q < 4; ++q) {
                x[q] = x0[q]; x[4 + q] = x1[q]; x[8 + q] = x2[q]; x[12 + q] = x3[q];
            }
            float d0 = dv[0], d1 = dv[1], d2 = dv[2], d3 = dv[3];
            #pragma unroll
            for (int e = 0; e < 16; ++e) {
                d0 += x[e] * M[e][0];
                d1 += x[e] * M[e][1];
                d2 += x[e] * M[e][2];
                d3 += x[e] * M[e][3];
            }
            v[0] += d0; v[1] += d1; v[2] += d2; v[3] += d3;
        }
        __builtin_nontemporal_store(v, out4 + (size_t)row * F4_PER_ROW + c);
    }
}

extern "C" void kernel_launch(void* const* d_in, const int* in_sizes, int n_in,
                              void* d_out, int out_size, void* d_ws, size_t ws_size,
                              hipStream_t stream) {
    const float* base = (const float*)d_in[0];
    const float* Wp   = (const float*)d_in[1];
    const float* bp   = (const float*)d_in[2];
    const float* Ws   = (const float*)d_in[3];
    const float* bs   = (const float*)d_in[4];
    float* out = (float*)d_out;

    const int B = in_sizes[0] / 768;
    int ngroups = (B + ROWS_PER_ITER - 1) / ROWS_PER_ITER;
    int grid = ngroups < MAX_BLOCKS ? ngroups : MAX_BLOCKS;

    multi_mini_interv_kernel<<<grid, BLOCK, 0, stream>>>(base, Wp, bp, Ws, bs, out, B);
}